// Round 14
// baseline (413.968 us; speedup 1.0000x reference)
//
#include <hip/hip_runtime.h>

#define N_PTS 1600
#define NSIDE 40
#define SNUM  512
#define BNUM  64
#define C1D   20
#define WID   128

typedef _Float16 h8  __attribute__((ext_vector_type(8)));
typedef _Float16 h4  __attribute__((ext_vector_type(4)));
typedef __fp16   h2v __attribute__((ext_vector_type(2)));   // type for cvt_pkrtz
typedef float    f4  __attribute__((ext_vector_type(4)));

__device__ __forceinline__ float silu_f(float x){ return x / (1.f + __expf(-x)); }
__device__ __forceinline__ void fma4(float4& a, float s, const float4 w){
    a.x += s*w.x; a.y += s*w.y; a.z += s*w.z; a.w += s*w.w;
}

// ---------------------------------------------------------------------------
// KA: blocks 0..319: filt2[s][c*128+w] = h2[s] @ s_w2 + s_b2 (h2 inline).
//     blocks 320..369: pack data -> dataA f16 MFMA A-frags (verified r4/r6).
//     block 370: pack MLP weights for B-frags (r10) + ZERO out2g/ticket
//     (replaces the host-side hipMemsetAsync; stream order makes this safe).
// ---------------------------------------------------------------------------
__global__ __launch_bounds__(256) void ka_prep(
    const float* __restrict__ data, const float* __restrict__ v0,
    const float* __restrict__ s_w1, const float* __restrict__ s_b1,
    const float* __restrict__ s_w2, const float* __restrict__ s_b2,
    const float* __restrict__ w1, const float* __restrict__ b1,
    const float* __restrict__ w2, const float* __restrict__ b2,
    const float* __restrict__ w3, const float* __restrict__ b3,
    _Float16* __restrict__ dataA, float* __restrict__ f2g,
    _Float16* __restrict__ wPackA, float* __restrict__ bPackA,
    float* __restrict__ out2g, unsigned int* __restrict__ ticket)
{
    const int t  = threadIdx.x;
    const int bx = blockIdx.x;
    if (bx == 370) {
        const float* wsrc[3] = { w1, w2, w3 };
        const float* bsrc[3] = { b1, b2, b3 };
        for (int v = t; v < 3072; v += 256) {
            const int l = v >> 10, rem = v & 1023;
            const int cout = rem >> 5, cin = rem & 31;
            float x = 0.f;
            if (cout < 20 && cin < 20) x = wsrc[l][cin * 20 + cout];
            wPackA[v] = (_Float16)x;
        }
        if (t < 96) {
            const int l = t >> 5, cout = t & 31;
            bPackA[t] = (cout < 20) ? bsrc[l][cout] : 0.f;
        }
        // zero the k2 accumulator + ticket (k2 runs 2 launches later in-stream)
        for (int v = t; v < 8192; v += 256) out2g[v] = 0.f;
        if (t == 0) *ticket = 0u;
        return;
    }
    if (bx >= 320) {
        const int o  = (bx - 320) * 256 + t;       // 0..12799
        const int L  = o & 63, cm = o >> 6;        // cm 0..199
        const int mt = cm & 3, ch = cm >> 2;       // ch 0..49
        const int b  = mt * 16 + (L & 15);
        const int nb = ch * 32 + (L >> 4) * 8;
        const float* src = data + b * N_PTS + nb;
        h8 v;
        #pragma unroll
        for (int j = 0; j < 8; j++) v[j] = (_Float16)src[j];
        *(h8*)(dataA + (size_t)o * 8) = v;
        return;
    }
    const int st  = bx / 10, ct = bx - st * 10;
    const int s0  = st * 16;
    const int col = ct * 256 + t;
    __shared__ __align__(16) float h2t[128][20];   // [i][ss] pad 20

    for (int idx = t; idx < 2048; idx += 256) {
        const int ss = idx >> 7, j = idx & 127;
        float acc = s_b1[j];
        #pragma unroll
        for (int d = 0; d < 8; d++) {
            const float val = v0[(s0 + ss) * 8 + d];
            float sv, cv;
            __sincosf(val, &sv, &cv);
            #pragma unroll
            for (int k = 0; k < 5; k++) {
                acc += sv * s_w1[(d*10 + k)     * WID + j];
                acc += cv * s_w1[(d*10 + 5 + k) * WID + j];
                const float ns = 2.f * sv * cv;
                const float nc = 1.f - 2.f * sv * sv;
                sv = ns; cv = nc;
            }
        }
        h2t[j][ss] = silu_f(acc);
    }
    __syncthreads();

    float4 acc[4];
    #pragma unroll
    for (int qq = 0; qq < 4; qq++) acc[qq] = make_float4(0.f, 0.f, 0.f, 0.f);
    #pragma unroll 4
    for (int i = 0; i < 128; i++) {
        const float wv = s_w2[i * 2560 + col];
        const float4* hh = (const float4*)&h2t[i][0];
        #pragma unroll
        for (int qq = 0; qq < 4; qq++) fma4(acc[qq], wv, hh[qq]);
    }
    const float bias = s_b2[col];
    const float* af = (const float*)acc;
    #pragma unroll
    for (int ss = 0; ss < 16; ss++)
        f2g[(s0 + ss) * 2560 + col] = af[ss] + bias;
}

// ---------------------------------------------------------------------------
// embed: sinusoidal embedding of projected point (single point)
// ---------------------------------------------------------------------------
__device__ __forceinline__ void embed_pt(int n, const float Hm[9], h2v e2[10])
{
    const int i = n / NSIDE;
    const int j = n - i * NSIDE;
    const float x = -1.f + (float)i * (2.f/39.f);
    const float y = -1.f + (float)j * (2.f/39.f);
    const float y0 = Hm[0]*x + Hm[1]*y + Hm[2];
    const float y1 = Hm[3]*x + Hm[4]*y + Hm[5];
    const float y2 = Hm[6]*x + Hm[7]*y + Hm[8];
    const float inv = 1.f / y2;
    const float t0 = y0 * inv, t1 = y1 * inv;
    float e[20];
    float sv0, cv0, sv1, cv1;
    __sincosf(t0, &sv0, &cv0);
    __sincosf(t1, &sv1, &cv1);
    #pragma unroll
    for (int k = 0; k < 5; k++) {
        e[k] = sv0; e[5+k] = cv0; e[10+k] = sv1; e[15+k] = cv1;
        const float ns0 = 2.f*sv0*cv0, nc0 = 1.f - 2.f*sv0*sv0; sv0 = ns0; cv0 = nc0;
        const float ns1 = 2.f*sv1*cv1, nc1 = 1.f - 2.f*sv1*sv1; sv1 = ns1; cv1 = nc1;
    }
    #pragma unroll
    for (int k = 0; k < 10; k++)
        e2[k] = __builtin_amdgcn_cvt_pkrtz(e[2*k], e[2*k+1]);
}

#define ASTRIDE 40   // act row stride in halves: 80 B, 16B-aligned rows (r10)

// ---------------------------------------------------------------------------
// K1: EXACT r10/r13 structure (50.0 µs measured) — unchanged this round.
// ---------------------------------------------------------------------------
__global__ __launch_bounds__(256) void k1_filt_z(
    const _Float16* __restrict__ dataA, const float* __restrict__ v_last,
    const _Float16* __restrict__ wPackA, const float* __restrict__ bPackA,
    float* __restrict__ zpart)
{
    const int s    = blockIdx.x & 511;
    const int half = blockIdx.x >> 9;
    const int nb0  = half * 800;
    const int t    = threadIdx.x;
    const int lane = t & 63;
    const int w    = t >> 6;
    const int q    = lane >> 4;
    const int l15  = lane & 15;

    __shared__ __align__(16) unsigned char pool[21504];  // act[256][40] f16 / red f32
    __shared__ __align__(16) _Float16 filtB[20 * 264];   // 10560 B
    _Float16* act = (_Float16*)pool;
    float*    red = (float*)pool;

    // weight B-frags + biases: resident in registers whole kernel
    h8 wf[3][2]; float bv[3][2];
    #pragma unroll
    for (int l = 0; l < 3; l++)
        #pragma unroll
        for (int nt = 0; nt < 2; nt++) {
            wf[l][nt] = *(const h8*)(wPackA + (((l*2+nt)*16 + l15) * 32 + q*8));
            bv[l][nt] = bPackA[(l*2+nt)*16 + l15];
        }

    float Hm[9];
    #pragma unroll
    for (int k = 0; k < 9; k++) Hm[k] = (k == 0 || k == 4 || k == 8) ? 1.f : 0.f;
    #pragma unroll
    for (int k = 0; k < 8; k++) Hm[k] += 0.1f * v_last[s*8 + k];

    f4 zacc[4][2];
    #pragma unroll
    for (int mt = 0; mt < 4; mt++) { zacc[mt][0] = (f4)(0.f); zacc[mt][1] = (f4)(0.f); }
    const f4 zero4 = (f4)(0.f);

    // zero K-pad cols 20..31 of all 256 rows (once; never rewritten)
    {
        unsigned long long* pz = (unsigned long long*)(act + t*ASTRIDE + 20);
        pz[0] = 0ull; pz[1] = 0ull; pz[2] = 0ull;
    }

    for (int base = 0; base < 800; base += 256) {
        const int tn = min(256, 800 - base);       // 256,256,256,32
        if (t < tn) {
            h2v e2[10];
            embed_pt(nb0 + base + t, Hm, e2);
            #pragma unroll
            for (int k = 0; k < 10; k++)
                *(h2v*)(act + t*ASTRIDE + 2*k) = e2[k];
        }
        __syncthreads();

        // ---- 3 MFMA MLP layers, in-place, strided m-tiles (r10 shape) ----
        const int nmt = tn >> 4;                   // 16 or 2
        #pragma unroll
        for (int l = 0; l < 3; l++) {
            for (int mt = w; mt < nmt; mt += 4) {
                const int r0 = mt * 16;
                const h8 af = *(const h8*)(act + (r0 + l15)*ASTRIDE + q*8);
                f4 D0 = __builtin_amdgcn_mfma_f32_16x16x32_f16(af, wf[l][0], zero4, 0, 0, 0);
                f4 D1 = __builtin_amdgcn_mfma_f32_16x16x32_f16(af, wf[l][1], zero4, 0, 0, 0);
                if (l < 2) {
                    #pragma unroll
                    for (int r = 0; r < 4; r++) {
                        const int p = r0 + q*4 + r;
                        act[p*ASTRIDE + l15] = (_Float16)silu_f(D0[r] + bv[l][0]);
                        if (l15 < 4)
                            act[p*ASTRIDE + 16 + l15] = (_Float16)silu_f(D1[r] + bv[l][1]);
                    }
                } else {
                    h4 p0, p1;
                    #pragma unroll
                    for (int r = 0; r < 4; r++) {
                        p0[r] = (_Float16)(D0[r] + bv[2][0]);
                        p1[r] = (_Float16)(D1[r] + bv[2][1]);
                    }
                    *(h4*)(filtB + l15*264 + r0 + q*4) = p0;
                    if (l15 < 4)
                        *(h4*)(filtB + (16 + l15)*264 + r0 + q*4) = p1;
                }
            }
        }
        __syncthreads();   // filtB ready for all waves

        // ---- z-GEMM: MFMA with global dataA A-frags (verified r5-r13) ----
        const int nkc = tn >> 5;   // 8,8,8,1
        const int r1row = (l15 < 4) ? (16 + l15) : 0;
        for (int kc = w; kc < nkc; kc += 4) {
            const int gchunk = ((nb0 + base) >> 5) + kc;
            const h8 bf0 = *(const h8*)(filtB + l15  *264 + kc*32 + q*8);
            const h8 bf1 = *(const h8*)(filtB + r1row*264 + kc*32 + q*8);
            #pragma unroll
            for (int mt = 0; mt < 4; mt++) {
                const h8 afz = *(const h8*)(dataA + ((size_t)(gchunk*4 + mt)*64 + lane)*8);
                zacc[mt][0] = __builtin_amdgcn_mfma_f32_16x16x32_f16(afz, bf0, zacc[mt][0], 0, 0, 0);
                zacc[mt][1] = __builtin_amdgcn_mfma_f32_16x16x32_f16(afz, bf1, zacc[mt][1], 0, 0, 0);
            }
        }
        __syncthreads();   // protect filtB + act for next tile
    }

    // cross-wave K-reduction (red overlays act; safe after trailing barrier)
    #pragma unroll
    for (int mt = 0; mt < 4; mt++) {
        #pragma unroll
        for (int r = 0; r < 4; r++) {
            const int b = mt*16 + q*4 + r;
            red[(w*64 + b)*21 + l15] = zacc[mt][0][r];
            if (l15 < 4) red[(w*64 + b)*21 + 16 + l15] = zacc[mt][1][r];
        }
    }
    __syncthreads();
    for (int v = t; v < 1280; v += 256) {
        const int c = v >> 6, b = v & 63;
        const float sum = red[b*21 + c] + red[(64+b)*21 + c]
                        + red[(128+b)*21 + c] + red[(192+b)*21 + c];
        zpart[(half*512 + s)*1280 + v] = sum;   // raw; silu + /N applied in k2
    }
}

// ---------------------------------------------------------------------------
// K2+K3 fused: grid 256. Each block: combine zpart halves + silu + /N,
// contract vs filt2, atomicAdd into out2g. Then fence + ticket; the LAST
// block (ticket==255) runs the FC tail for all 64 b, reading out2g via
// atomicAdd(p, 0.f) (device-scope L2 reads — safe vs L1 staleness, G16).
// ---------------------------------------------------------------------------
__global__ __launch_bounds__(256) void k2_contract_tail(
    const float* __restrict__ zg, const float* __restrict__ f2g,
    float* __restrict__ out2g, unsigned int* __restrict__ ticket,
    const float* __restrict__ fc1w, const float* __restrict__ fc1b,
    const float* __restrict__ fc2w, const float* __restrict__ fc2b,
    const float* __restrict__ pw,   const float* __restrict__ pb,
    float* __restrict__ out)
{
    const int blk = blockIdx.x;
    const int sg  = blk >> 1;
    const int wh  = blk & 1;
    const int s0  = sg * 4;
    const int w0  = wh * 64;
    const int t   = threadIdx.x;
    __shared__ __align__(16) float zl[4*1280];   // [sp][c][b]
    __shared__ __align__(16) float fl[4*20*64];  // [sp][c][w64]
    #pragma unroll
    for (int sp = 0; sp < 4; sp++) {
        const int srow = (s0 + sp) * 1280;
        for (int r = t; r < 1280; r += 256) {
            const float a0 = zg[srow + r];
            const float a1 = zg[512*1280 + srow + r];
            zl[sp*1280 + r] = silu_f((a0 + a1) * (1.f / (float)N_PTS));
        }
        for (int u = t; u < 1280; u += 256) {
            const int c = u >> 6, ww = u & 63;
            fl[sp*1280 + u] = f2g[(s0 + sp)*2560 + c*128 + w0 + ww];
        }
    }
    __syncthreads();
    const int ww = t & 63, bh = t >> 6;
    float4 acc[4];
    #pragma unroll
    for (int qq = 0; qq < 4; qq++) acc[qq] = make_float4(0.f, 0.f, 0.f, 0.f);
    #pragma unroll 4
    for (int sc = 0; sc < 80; sc++) {
        const float f = fl[sc * 64 + ww];
        const float4* zz = (const float4*)&zl[sc * 64 + bh * 16];
        #pragma unroll
        for (int qq = 0; qq < 4; qq++) fma4(acc[qq], f, zz[qq]);
    }
    const float* af = (const float*)acc;
    #pragma unroll
    for (int idx = 0; idx < 16; idx++) {
        const int b = bh * 16 + idx;
        atomicAdd(&out2g[b * 128 + w0 + ww], af[idx]);
    }

    // ---- ticket: last block runs the FC tail ----
    __threadfence();                 // publish this thread's atomics (L2)
    __syncthreads();                 // all threads of block have fenced
    __shared__ unsigned int my_ticket;
    if (t == 0) my_ticket = atomicAdd(ticket, 1u);
    __syncthreads();
    if (my_ticket != 255u) return;

    // tail: 2 b per pass (t>>7 selects b), col = t&127
    __shared__ float zb2[2][128], r1s[2][128], r2s[2][128];
    const int bh2 = t >> 7, col = t & 127;
    for (int b2 = 0; b2 < 64; b2 += 2) {
        const int b = b2 + bh2;
        // device-scope read of the fully-reduced accumulator
        zb2[bh2][col] = atomicAdd(&out2g[b * 128 + col], 0.f) * (1.f / (float)SNUM);
        __syncthreads();
        float a = fc1b[col];
        #pragma unroll 8
        for (int i = 0; i < 128; i++) a += zb2[bh2][i] * fc1w[i * 128 + col];
        r1s[bh2][col] = silu_f(a) + zb2[bh2][col];
        __syncthreads();
        a = fc2b[col];
        #pragma unroll 8
        for (int i = 0; i < 128; i++) a += r1s[bh2][i] * fc2w[i * 128 + col];
        r2s[bh2][col] = silu_f(a) + r1s[bh2][col];
        __syncthreads();
        if (col < 10) {
            float o = pb[col];
            #pragma unroll 8
            for (int i = 0; i < 128; i++) o += r2s[bh2][i] * pw[i * 10 + col];
            out[b * 10 + col] = o;
        }
        __syncthreads();
    }
}

extern "C" void kernel_launch(void* const* d_in, const int* in_sizes, int n_in,
                              void* d_out, int out_size, void* d_ws, size_t ws_size,
                              hipStream_t stream) {
    const float* data   = (const float*)d_in[0];
    const float* v0     = (const float*)d_in[1];
    const float* v_last = (const float*)d_in[2];
    const float* fl_w1  = (const float*)d_in[3];
    const float* fl_b1  = (const float*)d_in[4];
    const float* fl_w2  = (const float*)d_in[5];
    const float* fl_b2  = (const float*)d_in[6];
    const float* fl_w3  = (const float*)d_in[7];
    const float* fl_b3  = (const float*)d_in[8];
    const float* s_w1   = (const float*)d_in[9];
    const float* s_b1   = (const float*)d_in[10];
    const float* s_w2   = (const float*)d_in[11];
    const float* s_b2   = (const float*)d_in[12];
    const float* fc1_w  = (const float*)d_in[13];
    const float* fc1_b  = (const float*)d_in[14];
    const float* fc2_w  = (const float*)d_in[15];
    const float* fc2_b  = (const float*)d_in[16];
    const float* pool_w = (const float*)d_in[17];
    const float* pool_b = (const float*)d_in[18];
    float* out = (float*)d_out;

    float* ws        = (float*)d_ws;
    _Float16* dataA  = (_Float16*)ws;        // 102400 halves = 51200 float slots
    float* zpart  = ws    + 51200;           // 2*655360 [half][s][c][b] raw
    float* f2g    = zpart + 1310720;         // 1310720  [s][c*128+w]
    float* out2g  = f2g   + 1310720;         // 8192 [b][w] atomic accumulator
    _Float16* wPackA = (_Float16*)(out2g + 8192);    // 3072 halves
    float* bPackA = out2g + 8192 + 1536;     // 96 floats
    unsigned int* ticket = (unsigned int*)(bPackA + 96);
    // total ~10.9 MB

    ka_prep    <<<371, 256, 0, stream>>>(data, v0, s_w1, s_b1, s_w2, s_b2,
                                         fl_w1, fl_b1, fl_w2, fl_b2, fl_w3, fl_b3,
                                         dataA, f2g, wPackA, bPackA, out2g, ticket);
    k1_filt_z  <<<1024, 256, 0, stream>>>(dataA, v_last, wPackA, bPackA, zpart);
    k2_contract_tail<<<256, 256, 0, stream>>>(zpart, f2g, out2g, ticket,
                                              fc1_w, fc1_b, fc2_w, fc2_b,
                                              pool_w, pool_b, out);
}

// Round 15
// 197.977 us; speedup vs baseline: 2.0910x; 2.0910x over previous
//
#include <hip/hip_runtime.h>

#define N_PTS 1600
#define NSIDE 40
#define SNUM  512
#define BNUM  64
#define C1D   20
#define WID   128

typedef _Float16 h8  __attribute__((ext_vector_type(8)));
typedef _Float16 h4  __attribute__((ext_vector_type(4)));
typedef __fp16   h2v __attribute__((ext_vector_type(2)));   // type for cvt_pkrtz
typedef float    f4  __attribute__((ext_vector_type(4)));

__device__ __forceinline__ float silu_f(float x){ return x / (1.f + __expf(-x)); }
__device__ __forceinline__ void fma4(float4& a, float s, const float4 w){
    a.x += s*w.x; a.y += s*w.y; a.z += s*w.z; a.w += s*w.w;
}

// ---------------------------------------------------------------------------
// KA: blocks 0..319: filt2[s][c*128+w] = h2[s] @ s_w2 + s_b2 (h2 inline).
//     blocks 320..369: pack data -> dataA f16 MFMA A-frags (verified r4/r6).
//     block 370: pack MLP weights transposed for B-frags (verified r10).
// ---------------------------------------------------------------------------
__global__ __launch_bounds__(256) void ka_prep(
    const float* __restrict__ data, const float* __restrict__ v0,
    const float* __restrict__ s_w1, const float* __restrict__ s_b1,
    const float* __restrict__ s_w2, const float* __restrict__ s_b2,
    const float* __restrict__ w1, const float* __restrict__ b1,
    const float* __restrict__ w2, const float* __restrict__ b2,
    const float* __restrict__ w3, const float* __restrict__ b3,
    _Float16* __restrict__ dataA, float* __restrict__ f2g,
    _Float16* __restrict__ wPackA, float* __restrict__ bPackA)
{
    const int t  = threadIdx.x;
    const int bx = blockIdx.x;
    if (bx == 370) {
        const float* wsrc[3] = { w1, w2, w3 };
        const float* bsrc[3] = { b1, b2, b3 };
        for (int v = t; v < 3072; v += 256) {
            const int l = v >> 10, rem = v & 1023;
            const int cout = rem >> 5, cin = rem & 31;
            float x = 0.f;
            if (cout < 20 && cin < 20) x = wsrc[l][cin * 20 + cout];
            wPackA[v] = (_Float16)x;
        }
        if (t < 96) {
            const int l = t >> 5, cout = t & 31;
            bPackA[t] = (cout < 20) ? bsrc[l][cout] : 0.f;
        }
        return;
    }
    if (bx >= 320) {
        const int o  = (bx - 320) * 256 + t;       // 0..12799
        const int L  = o & 63, cm = o >> 6;        // cm 0..199
        const int mt = cm & 3, ch = cm >> 2;       // ch 0..49
        const int b  = mt * 16 + (L & 15);
        const int nb = ch * 32 + (L >> 4) * 8;
        const float* src = data + b * N_PTS + nb;
        h8 v;
        #pragma unroll
        for (int j = 0; j < 8; j++) v[j] = (_Float16)src[j];
        *(h8*)(dataA + (size_t)o * 8) = v;
        return;
    }
    const int st  = bx / 10, ct = bx - st * 10;
    const int s0  = st * 16;
    const int col = ct * 256 + t;
    __shared__ __align__(16) float h2t[128][20];   // [i][ss] pad 20

    for (int idx = t; idx < 2048; idx += 256) {
        const int ss = idx >> 7, j = idx & 127;
        float acc = s_b1[j];
        #pragma unroll
        for (int d = 0; d < 8; d++) {
            const float val = v0[(s0 + ss) * 8 + d];
            float sv, cv;
            __sincosf(val, &sv, &cv);
            #pragma unroll
            for (int k = 0; k < 5; k++) {
                acc += sv * s_w1[(d*10 + k)     * WID + j];
                acc += cv * s_w1[(d*10 + 5 + k) * WID + j];
                const float ns = 2.f * sv * cv;
                const float nc = 1.f - 2.f * sv * sv;
                sv = ns; cv = nc;
            }
        }
        h2t[j][ss] = silu_f(acc);
    }
    __syncthreads();

    float4 acc[4];
    #pragma unroll
    for (int qq = 0; qq < 4; qq++) acc[qq] = make_float4(0.f, 0.f, 0.f, 0.f);
    #pragma unroll 4
    for (int i = 0; i < 128; i++) {
        const float wv = s_w2[i * 2560 + col];
        const float4* hh = (const float4*)&h2t[i][0];
        #pragma unroll
        for (int qq = 0; qq < 4; qq++) fma4(acc[qq], wv, hh[qq]);
    }
    const float bias = s_b2[col];
    const float* af = (const float*)acc;
    #pragma unroll
    for (int ss = 0; ss < 16; ss++)
        f2g[(s0 + ss) * 2560 + col] = af[ss] + bias;
}

// ---------------------------------------------------------------------------
// embed: sinusoidal embedding of projected point (single point)
// ---------------------------------------------------------------------------
__device__ __forceinline__ void embed_pt(int n, const float Hm[9], h2v e2[10])
{
    const int i = n / NSIDE;
    const int j = n - i * NSIDE;
    const float x = -1.f + (float)i * (2.f/39.f);
    const float y = -1.f + (float)j * (2.f/39.f);
    const float y0 = Hm[0]*x + Hm[1]*y + Hm[2];
    const float y1 = Hm[3]*x + Hm[4]*y + Hm[5];
    const float y2 = Hm[6]*x + Hm[7]*y + Hm[8];
    const float inv = 1.f / y2;
    const float t0 = y0 * inv, t1 = y1 * inv;
    float e[20];
    float sv0, cv0, sv1, cv1;
    __sincosf(t0, &sv0, &cv0);
    __sincosf(t1, &sv1, &cv1);
    #pragma unroll
    for (int k = 0; k < 5; k++) {
        e[k] = sv0; e[5+k] = cv0; e[10+k] = sv1; e[15+k] = cv1;
        const float ns0 = 2.f*sv0*cv0, nc0 = 1.f - 2.f*sv0*sv0; sv0 = ns0; cv0 = nc0;
        const float ns1 = 2.f*sv1*cv1, nc1 = 1.f - 2.f*sv1*sv1; sv1 = ns1; cv1 = nc1;
    }
    #pragma unroll
    for (int k = 0; k < 10; k++)
        e2[k] = __builtin_amdgcn_cvt_pkrtz(e[2*k], e[2*k+1]);
}

#define ASTRIDE 40   // act row stride in halves: 80 B, 16B-aligned rows (r10)

// ---------------------------------------------------------------------------
// K1: EXACT r10/r13 structure (50.0 µs measured) — embed -> barrier -> 3 MFMA
// MLP layers with runtime-strided m-tile loop -> barrier -> z-GEMM -> barrier.
// grid 1024 = (half, s), 800 pts/block, tiles of 256 (3x256 + 32 tail).
// zpart[half][s][c*64+b] raw sums; K2 combines + silu + /N.
// ---------------------------------------------------------------------------
__global__ __launch_bounds__(256) void k1_filt_z(
    const _Float16* __restrict__ dataA, const float* __restrict__ v_last,
    const _Float16* __restrict__ wPackA, const float* __restrict__ bPackA,
    float* __restrict__ zpart)
{
    const int s    = blockIdx.x & 511;
    const int half = blockIdx.x >> 9;
    const int nb0  = half * 800;
    const int t    = threadIdx.x;
    const int lane = t & 63;
    const int w    = t >> 6;
    const int q    = lane >> 4;
    const int l15  = lane & 15;

    __shared__ __align__(16) unsigned char pool[21504];  // act[256][40] f16 / red f32
    __shared__ __align__(16) _Float16 filtB[20 * 264];   // 10560 B
    _Float16* act = (_Float16*)pool;
    float*    red = (float*)pool;

    // weight B-frags + biases: resident in registers whole kernel
    h8 wf[3][2]; float bv[3][2];
    #pragma unroll
    for (int l = 0; l < 3; l++)
        #pragma unroll
        for (int nt = 0; nt < 2; nt++) {
            wf[l][nt] = *(const h8*)(wPackA + (((l*2+nt)*16 + l15) * 32 + q*8));
            bv[l][nt] = bPackA[(l*2+nt)*16 + l15];
        }

    float Hm[9];
    #pragma unroll
    for (int k = 0; k < 9; k++) Hm[k] = (k == 0 || k == 4 || k == 8) ? 1.f : 0.f;
    #pragma unroll
    for (int k = 0; k < 8; k++) Hm[k] += 0.1f * v_last[s*8 + k];

    f4 zacc[4][2];
    #pragma unroll
    for (int mt = 0; mt < 4; mt++) { zacc[mt][0] = (f4)(0.f); zacc[mt][1] = (f4)(0.f); }
    const f4 zero4 = (f4)(0.f);

    // zero K-pad cols 20..31 of all 256 rows (once; never rewritten)
    {
        unsigned long long* pz = (unsigned long long*)(act + t*ASTRIDE + 20);
        pz[0] = 0ull; pz[1] = 0ull; pz[2] = 0ull;
    }

    for (int base = 0; base < 800; base += 256) {
        const int tn = min(256, 800 - base);       // 256,256,256,32
        if (t < tn) {
            h2v e2[10];
            embed_pt(nb0 + base + t, Hm, e2);
            #pragma unroll
            for (int k = 0; k < 10; k++)
                *(h2v*)(act + t*ASTRIDE + 2*k) = e2[k];
        }
        __syncthreads();

        // ---- 3 MFMA MLP layers, in-place, strided m-tiles (r10 shape) ----
        const int nmt = tn >> 4;                   // 16 or 2
        #pragma unroll
        for (int l = 0; l < 3; l++) {
            for (int mt = w; mt < nmt; mt += 4) {
                const int r0 = mt * 16;
                const h8 af = *(const h8*)(act + (r0 + l15)*ASTRIDE + q*8);
                f4 D0 = __builtin_amdgcn_mfma_f32_16x16x32_f16(af, wf[l][0], zero4, 0, 0, 0);
                f4 D1 = __builtin_amdgcn_mfma_f32_16x16x32_f16(af, wf[l][1], zero4, 0, 0, 0);
                if (l < 2) {
                    #pragma unroll
                    for (int r = 0; r < 4; r++) {
                        const int p = r0 + q*4 + r;
                        act[p*ASTRIDE + l15] = (_Float16)silu_f(D0[r] + bv[l][0]);
                        if (l15 < 4)
                            act[p*ASTRIDE + 16 + l15] = (_Float16)silu_f(D1[r] + bv[l][1]);
                    }
                } else {
                    h4 p0, p1;
                    #pragma unroll
                    for (int r = 0; r < 4; r++) {
                        p0[r] = (_Float16)(D0[r] + bv[2][0]);
                        p1[r] = (_Float16)(D1[r] + bv[2][1]);
                    }
                    *(h4*)(filtB + l15*264 + r0 + q*4) = p0;
                    if (l15 < 4)
                        *(h4*)(filtB + (16 + l15)*264 + r0 + q*4) = p1;
                }
            }
        }
        __syncthreads();   // filtB ready for all waves

        // ---- z-GEMM: MFMA with global dataA A-frags (verified r5-r13) ----
        const int nkc = tn >> 5;   // 8,8,8,1
        const int r1row = (l15 < 4) ? (16 + l15) : 0;
        for (int kc = w; kc < nkc; kc += 4) {
            const int gchunk = ((nb0 + base) >> 5) + kc;
            const h8 bf0 = *(const h8*)(filtB + l15  *264 + kc*32 + q*8);
            const h8 bf1 = *(const h8*)(filtB + r1row*264 + kc*32 + q*8);
            #pragma unroll
            for (int mt = 0; mt < 4; mt++) {
                const h8 afz = *(const h8*)(dataA + ((size_t)(gchunk*4 + mt)*64 + lane)*8);
                zacc[mt][0] = __builtin_amdgcn_mfma_f32_16x16x32_f16(afz, bf0, zacc[mt][0], 0, 0, 0);
                zacc[mt][1] = __builtin_amdgcn_mfma_f32_16x16x32_f16(afz, bf1, zacc[mt][1], 0, 0, 0);
            }
        }
        __syncthreads();   // protect filtB + act for next tile
    }

    // cross-wave K-reduction (red overlays act; safe after trailing barrier)
    #pragma unroll
    for (int mt = 0; mt < 4; mt++) {
        #pragma unroll
        for (int r = 0; r < 4; r++) {
            const int b = mt*16 + q*4 + r;
            red[(w*64 + b)*21 + l15] = zacc[mt][0][r];
            if (l15 < 4) red[(w*64 + b)*21 + 16 + l15] = zacc[mt][1][r];
        }
    }
    __syncthreads();
    for (int v = t; v < 1280; v += 256) {
        const int c = v >> 6, b = v & 63;
        const float sum = red[b*21 + c] + red[(64+b)*21 + c]
                        + red[(128+b)*21 + c] + red[(192+b)*21 + c];
        zpart[(half*512 + s)*1280 + v] = sum;   // raw; silu + /N applied in k2
    }
}

// ---------------------------------------------------------------------------
// K2: grid 256 = (sgrp 128) x (whalf 2). Block: 4 s, 64 w.
// Combines zpart halves + silu + /N, contracts vs filt2, atomicAdd into
// out2g[64][128] (fp32 accumulator, zeroed by hipMemsetAsync pre-launch).
// ---------------------------------------------------------------------------
__global__ __launch_bounds__(256) void k2_contract(
    const float* __restrict__ zg, const float* __restrict__ f2g,
    float* __restrict__ out2g)
{
    const int blk = blockIdx.x;
    const int sg  = blk >> 1;
    const int wh  = blk & 1;
    const int s0  = sg * 4;
    const int w0  = wh * 64;
    const int t   = threadIdx.x;
    __shared__ __align__(16) float zl[4*1280];   // [sp][c][b]
    __shared__ __align__(16) float fl[4*20*64];  // [sp][c][w64]
    #pragma unroll
    for (int sp = 0; sp < 4; sp++) {
        const int srow = (s0 + sp) * 1280;
        for (int r = t; r < 1280; r += 256) {
            const float a0 = zg[srow + r];
            const float a1 = zg[512*1280 + srow + r];
            zl[sp*1280 + r] = silu_f((a0 + a1) * (1.f / (float)N_PTS));
        }
        for (int u = t; u < 1280; u += 256) {
            const int c = u >> 6, ww = u & 63;
            fl[sp*1280 + u] = f2g[(s0 + sp)*2560 + c*128 + w0 + ww];
        }
    }
    __syncthreads();
    const int ww = t & 63, bh = t >> 6;
    float4 acc[4];
    #pragma unroll
    for (int qq = 0; qq < 4; qq++) acc[qq] = make_float4(0.f, 0.f, 0.f, 0.f);
    #pragma unroll 4
    for (int sc = 0; sc < 80; sc++) {
        const float f = fl[sc * 64 + ww];
        const float4* zz = (const float4*)&zl[sc * 64 + bh * 16];
        #pragma unroll
        for (int qq = 0; qq < 4; qq++) fma4(acc[qq], f, zz[qq]);
    }
    const float* af = (const float*)acc;
    #pragma unroll
    for (int idx = 0; idx < 16; idx++) {
        const int b = bh * 16 + idx;
        atomicAdd(&out2g[b * 128 + w0 + ww], af[idx]);
    }
}

// ---------------------------------------------------------------------------
// K3: FC tail only (out2 already reduced by k2 atomics).
// ---------------------------------------------------------------------------
__global__ __launch_bounds__(128) void k3_tail(
    const float* __restrict__ out2g,
    const float* __restrict__ fc1w, const float* __restrict__ fc1b,
    const float* __restrict__ fc2w, const float* __restrict__ fc2b,
    const float* __restrict__ pw,   const float* __restrict__ pb,
    float* __restrict__ out)
{
    const int b = blockIdx.x, t = threadIdx.x;
    __shared__ float zb[128], r1[128], r2[128];
    zb[t] = out2g[b * 128 + t] * (1.f / (float)SNUM);
    __syncthreads();
    float a = fc1b[t];
    #pragma unroll 8
    for (int i = 0; i < 128; i++) a += zb[i] * fc1w[i * 128 + t];
    r1[t] = silu_f(a) + zb[t];
    __syncthreads();
    a = fc2b[t];
    #pragma unroll 8
    for (int i = 0; i < 128; i++) a += r1[i] * fc2w[i * 128 + t];
    r2[t] = silu_f(a) + r1[t];
    __syncthreads();
    if (t < 10) {
        float o = pb[t];
        #pragma unroll 8
        for (int i = 0; i < 128; i++) o += r2[i] * pw[i * 10 + t];
        out[b * 10 + t] = o;
    }
}

extern "C" void kernel_launch(void* const* d_in, const int* in_sizes, int n_in,
                              void* d_out, int out_size, void* d_ws, size_t ws_size,
                              hipStream_t stream) {
    const float* data   = (const float*)d_in[0];
    const float* v0     = (const float*)d_in[1];
    const float* v_last = (const float*)d_in[2];
    const float* fl_w1  = (const float*)d_in[3];
    const float* fl_b1  = (const float*)d_in[4];
    const float* fl_w2  = (const float*)d_in[5];
    const float* fl_b2  = (const float*)d_in[6];
    const float* fl_w3  = (const float*)d_in[7];
    const float* fl_b3  = (const float*)d_in[8];
    const float* s_w1   = (const float*)d_in[9];
    const float* s_b1   = (const float*)d_in[10];
    const float* s_w2   = (const float*)d_in[11];
    const float* s_b2   = (const float*)d_in[12];
    const float* fc1_w  = (const float*)d_in[13];
    const float* fc1_b  = (const float*)d_in[14];
    const float* fc2_w  = (const float*)d_in[15];
    const float* fc2_b  = (const float*)d_in[16];
    const float* pool_w = (const float*)d_in[17];
    const float* pool_b = (const float*)d_in[18];
    float* out = (float*)d_out;

    float* ws        = (float*)d_ws;
    _Float16* dataA  = (_Float16*)ws;        // 102400 halves = 51200 float slots
    float* zpart  = ws    + 51200;           // 2*655360 [half][s][c][b] raw
    float* f2g    = zpart + 1310720;         // 1310720  [s][c*128+w]
    float* out2g  = f2g   + 1310720;         // 8192 [b][w] atomic accumulator
    _Float16* wPackA = (_Float16*)(out2g + 8192);    // 3072 halves
    float* bPackA = out2g + 8192 + 1536;     // 96 floats
    // total ~10.9 MB

    hipMemsetAsync(out2g, 0, 8192 * sizeof(float), stream);
    ka_prep    <<<371, 256, 0, stream>>>(data, v0, s_w1, s_b1, s_w2, s_b2,
                                         fl_w1, fl_b1, fl_w2, fl_b2, fl_w3, fl_b3,
                                         dataA, f2g, wPackA, bPackA);
    k1_filt_z  <<<1024, 256, 0, stream>>>(dataA, v_last, wPackA, bPackA, zpart);
    k2_contract<<<256, 256, 0, stream>>>(zpart, f2g, out2g);
    k3_tail    <<<64, 128, 0, stream>>>(out2g, fc1_w, fc1_b, fc2_w, fc2_b,
                                        pool_w, pool_b, out);
}

// Round 17
// 194.160 us; speedup vs baseline: 2.1321x; 1.0197x over previous
//
#include <hip/hip_runtime.h>

#define N_PTS 1600
#define NSIDE 40
#define SNUM  512
#define BNUM  64
#define C1D   20
#define WID   128

typedef _Float16 h8  __attribute__((ext_vector_type(8)));
typedef _Float16 h4  __attribute__((ext_vector_type(4)));
typedef __fp16   h2v __attribute__((ext_vector_type(2)));   // type for cvt_pkrtz
typedef float    f4  __attribute__((ext_vector_type(4)));

__device__ __forceinline__ float silu_f(float x){ return x / (1.f + __expf(-x)); }
__device__ __forceinline__ void fma4(float4& a, float s, const float4 w){
    a.x += s*w.x; a.y += s*w.y; a.z += s*w.z; a.w += s*w.w;
}

// ---------------------------------------------------------------------------
// KA: blocks 0..319: filt2[s][c*128+w] = h2[s] @ s_w2 + s_b2 (h2 inline).
//     blocks 320..369: pack data -> dataA f16 MFMA A-frags (verified r4/r6).
//     block 370: pack MLP weights transposed for B-frags (verified r10) and
//     zero out2g (r14-validated; replaces the hipMemsetAsync node — stream
//     order guarantees completion before k2's atomics two launches later).
// ---------------------------------------------------------------------------
__global__ __launch_bounds__(256) void ka_prep(
    const float* __restrict__ data, const float* __restrict__ v0,
    const float* __restrict__ s_w1, const float* __restrict__ s_b1,
    const float* __restrict__ s_w2, const float* __restrict__ s_b2,
    const float* __restrict__ w1, const float* __restrict__ b1,
    const float* __restrict__ w2, const float* __restrict__ b2,
    const float* __restrict__ w3, const float* __restrict__ b3,
    _Float16* __restrict__ dataA, float* __restrict__ f2g,
    _Float16* __restrict__ wPackA, float* __restrict__ bPackA,
    float* __restrict__ out2g)
{
    const int t  = threadIdx.x;
    const int bx = blockIdx.x;
    if (bx == 370) {
        const float* wsrc[3] = { w1, w2, w3 };
        const float* bsrc[3] = { b1, b2, b3 };
        for (int v = t; v < 3072; v += 256) {
            const int l = v >> 10, rem = v & 1023;
            const int cout = rem >> 5, cin = rem & 31;
            float x = 0.f;
            if (cout < 20 && cin < 20) x = wsrc[l][cin * 20 + cout];
            wPackA[v] = (_Float16)x;
        }
        if (t < 96) {
            const int l = t >> 5, cout = t & 31;
            bPackA[t] = (cout < 20) ? bsrc[l][cout] : 0.f;
        }
        for (int v = t; v < 8192; v += 256) out2g[v] = 0.f;
        return;
    }
    if (bx >= 320) {
        const int o  = (bx - 320) * 256 + t;       // 0..12799
        const int L  = o & 63, cm = o >> 6;        // cm 0..199
        const int mt = cm & 3, ch = cm >> 2;       // ch 0..49
        const int b  = mt * 16 + (L & 15);
        const int nb = ch * 32 + (L >> 4) * 8;
        const float* src = data + b * N_PTS + nb;
        h8 v;
        #pragma unroll
        for (int j = 0; j < 8; j++) v[j] = (_Float16)src[j];
        *(h8*)(dataA + (size_t)o * 8) = v;
        return;
    }
    const int st  = bx / 10, ct = bx - st * 10;
    const int s0  = st * 16;
    const int col = ct * 256 + t;
    __shared__ __align__(16) float h2t[128][20];   // [i][ss] pad 20

    for (int idx = t; idx < 2048; idx += 256) {
        const int ss = idx >> 7, j = idx & 127;
        float acc = s_b1[j];
        #pragma unroll
        for (int d = 0; d < 8; d++) {
            const float val = v0[(s0 + ss) * 8 + d];
            float sv, cv;
            __sincosf(val, &sv, &cv);
            #pragma unroll
            for (int k = 0; k < 5; k++) {
                acc += sv * s_w1[(d*10 + k)     * WID + j];
                acc += cv * s_w1[(d*10 + 5 + k) * WID + j];
                const float ns = 2.f * sv * cv;
                const float nc = 1.f - 2.f * sv * sv;
                sv = ns; cv = nc;
            }
        }
        h2t[j][ss] = silu_f(acc);
    }
    __syncthreads();

    float4 acc[4];
    #pragma unroll
    for (int qq = 0; qq < 4; qq++) acc[qq] = make_float4(0.f, 0.f, 0.f, 0.f);
    #pragma unroll 4
    for (int i = 0; i < 128; i++) {
        const float wv = s_w2[i * 2560 + col];
        const float4* hh = (const float4*)&h2t[i][0];
        #pragma unroll
        for (int qq = 0; qq < 4; qq++) fma4(acc[qq], wv, hh[qq]);
    }
    const float bias = s_b2[col];
    const float* af = (const float*)acc;
    #pragma unroll
    for (int ss = 0; ss < 16; ss++)
        f2g[(s0 + ss) * 2560 + col] = af[ss] + bias;
}

// ---------------------------------------------------------------------------
// embed: sinusoidal embedding of projected point (single point)
// ---------------------------------------------------------------------------
__device__ __forceinline__ void embed_pt(int n, const float Hm[9], h2v e2[10])
{
    const int i = n / NSIDE;
    const int j = n - i * NSIDE;
    const float x = -1.f + (float)i * (2.f/39.f);
    const float y = -1.f + (float)j * (2.f/39.f);
    const float y0 = Hm[0]*x + Hm[1]*y + Hm[2];
    const float y1 = Hm[3]*x + Hm[4]*y + Hm[5];
    const float y2 = Hm[6]*x + Hm[7]*y + Hm[8];
    const float inv = 1.f / y2;
    const float t0 = y0 * inv, t1 = y1 * inv;
    float e[20];
    float sv0, cv0, sv1, cv1;
    __sincosf(t0, &sv0, &cv0);
    __sincosf(t1, &sv1, &cv1);
    #pragma unroll
    for (int k = 0; k < 5; k++) {
        e[k] = sv0; e[5+k] = cv0; e[10+k] = sv1; e[15+k] = cv1;
        const float ns0 = 2.f*sv0*cv0, nc0 = 1.f - 2.f*sv0*sv0; sv0 = ns0; cv0 = nc0;
        const float ns1 = 2.f*sv1*cv1, nc1 = 1.f - 2.f*sv1*sv1; sv1 = ns1; cv1 = nc1;
    }
    #pragma unroll
    for (int k = 0; k < 10; k++)
        e2[k] = __builtin_amdgcn_cvt_pkrtz(e[2*k], e[2*k+1]);
}

#define ASTRIDE 40   // act row stride in halves: 80 B, 16B-aligned rows (r10)

// ---------------------------------------------------------------------------
// K1: EXACT r10/r13 structure (50.0 µs measured) — embed -> barrier -> 3 MFMA
// MLP layers with runtime-strided m-tile loop -> barrier -> z-GEMM -> barrier.
// grid 1024 = (half, s), 800 pts/block, tiles of 256 (3x256 + 32 tail).
// zpart[half][s][c*64+b] raw sums; K2 combines + silu + /N.
// ---------------------------------------------------------------------------
__global__ __launch_bounds__(256) void k1_filt_z(
    const _Float16* __restrict__ dataA, const float* __restrict__ v_last,
    const _Float16* __restrict__ wPackA, const float* __restrict__ bPackA,
    float* __restrict__ zpart)
{
    const int s    = blockIdx.x & 511;
    const int half = blockIdx.x >> 9;
    const int nb0  = half * 800;
    const int t    = threadIdx.x;
    const int lane = t & 63;
    const int w    = t >> 6;
    const int q    = lane >> 4;
    const int l15  = lane & 15;

    __shared__ __align__(16) unsigned char pool[21504];  // act[256][40] f16 / red f32
    __shared__ __align__(16) _Float16 filtB[20 * 264];   // 10560 B
    _Float16* act = (_Float16*)pool;
    float*    red = (float*)pool;

    // weight B-frags + biases: resident in registers whole kernel
    h8 wf[3][2]; float bv[3][2];
    #pragma unroll
    for (int l = 0; l < 3; l++)
        #pragma unroll
        for (int nt = 0; nt < 2; nt++) {
            wf[l][nt] = *(const h8*)(wPackA + (((l*2+nt)*16 + l15) * 32 + q*8));
            bv[l][nt] = bPackA[(l*2+nt)*16 + l15];
        }

    float Hm[9];
    #pragma unroll
    for (int k = 0; k < 9; k++) Hm[k] = (k == 0 || k == 4 || k == 8) ? 1.f : 0.f;
    #pragma unroll
    for (int k = 0; k < 8; k++) Hm[k] += 0.1f * v_last[s*8 + k];

    f4 zacc[4][2];
    #pragma unroll
    for (int mt = 0; mt < 4; mt++) { zacc[mt][0] = (f4)(0.f); zacc[mt][1] = (f4)(0.f); }
    const f4 zero4 = (f4)(0.f);

    // zero K-pad cols 20..31 of all 256 rows (once; never rewritten)
    {
        unsigned long long* pz = (unsigned long long*)(act + t*ASTRIDE + 20);
        pz[0] = 0ull; pz[1] = 0ull; pz[2] = 0ull;
    }

    for (int base = 0; base < 800; base += 256) {
        const int tn = min(256, 800 - base);       // 256,256,256,32
        if (t < tn) {
            h2v e2[10];
            embed_pt(nb0 + base + t, Hm, e2);
            #pragma unroll
            for (int k = 0; k < 10; k++)
                *(h2v*)(act + t*ASTRIDE + 2*k) = e2[k];
        }
        __syncthreads();

        // ---- 3 MFMA MLP layers, in-place, strided m-tiles (r10 shape) ----
        const int nmt = tn >> 4;                   // 16 or 2
        #pragma unroll
        for (int l = 0; l < 3; l++) {
            for (int mt = w; mt < nmt; mt += 4) {
                const int r0 = mt * 16;
                const h8 af = *(const h8*)(act + (r0 + l15)*ASTRIDE + q*8);
                f4 D0 = __builtin_amdgcn_mfma_f32_16x16x32_f16(af, wf[l][0], zero4, 0, 0, 0);
                f4 D1 = __builtin_amdgcn_mfma_f32_16x16x32_f16(af, wf[l][1], zero4, 0, 0, 0);
                if (l < 2) {
                    #pragma unroll
                    for (int r = 0; r < 4; r++) {
                        const int p = r0 + q*4 + r;
                        act[p*ASTRIDE + l15] = (_Float16)silu_f(D0[r] + bv[l][0]);
                        if (l15 < 4)
                            act[p*ASTRIDE + 16 + l15] = (_Float16)silu_f(D1[r] + bv[l][1]);
                    }
                } else {
                    h4 p0, p1;
                    #pragma unroll
                    for (int r = 0; r < 4; r++) {
                        p0[r] = (_Float16)(D0[r] + bv[2][0]);
                        p1[r] = (_Float16)(D1[r] + bv[2][1]);
                    }
                    *(h4*)(filtB + l15*264 + r0 + q*4) = p0;
                    if (l15 < 4)
                        *(h4*)(filtB + (16 + l15)*264 + r0 + q*4) = p1;
                }
            }
        }
        __syncthreads();   // filtB ready for all waves

        // ---- z-GEMM: MFMA with global dataA A-frags (verified r5-r15) ----
        const int nkc = tn >> 5;   // 8,8,8,1
        const int r1row = (l15 < 4) ? (16 + l15) : 0;
        for (int kc = w; kc < nkc; kc += 4) {
            const int gchunk = ((nb0 + base) >> 5) + kc;
            const h8 bf0 = *(const h8*)(filtB + l15  *264 + kc*32 + q*8);
            const h8 bf1 = *(const h8*)(filtB + r1row*264 + kc*32 + q*8);
            #pragma unroll
            for (int mt = 0; mt < 4; mt++) {
                const h8 afz = *(const h8*)(dataA + ((size_t)(gchunk*4 + mt)*64 + lane)*8);
                zacc[mt][0] = __builtin_amdgcn_mfma_f32_16x16x32_f16(afz, bf0, zacc[mt][0], 0, 0, 0);
                zacc[mt][1] = __builtin_amdgcn_mfma_f32_16x16x32_f16(afz, bf1, zacc[mt][1], 0, 0, 0);
            }
        }
        __syncthreads();   // protect filtB + act for next tile
    }

    // cross-wave K-reduction (red overlays act; safe after trailing barrier)
    #pragma unroll
    for (int mt = 0; mt < 4; mt++) {
        #pragma unroll
        for (int r = 0; r < 4; r++) {
            const int b = mt*16 + q*4 + r;
            red[(w*64 + b)*21 + l15] = zacc[mt][0][r];
            if (l15 < 4) red[(w*64 + b)*21 + 16 + l15] = zacc[mt][1][r];
        }
    }
    __syncthreads();
    for (int v = t; v < 1280; v += 256) {
        const int c = v >> 6, b = v & 63;
        const float sum = red[b*21 + c] + red[(64+b)*21 + c]
                        + red[(128+b)*21 + c] + red[(192+b)*21 + c];
        zpart[(half*512 + s)*1280 + v] = sum;   // raw; silu + /N applied in k2
    }
}

// ---------------------------------------------------------------------------
// K2: grid 256 = (sgrp 128) x (whalf 2). Block: 4 s, 64 w.
// Combines zpart halves + silu + /N, contracts vs filt2, atomicAdd into
// out2g[64][128] (fp32 accumulator, zeroed by ka_prep block 370).
// ---------------------------------------------------------------------------
__global__ __launch_bounds__(256) void k2_contract(
    const float* __restrict__ zg, const float* __restrict__ f2g,
    float* __restrict__ out2g)
{
    const int blk = blockIdx.x;
    const int sg  = blk >> 1;
    const int wh  = blk & 1;
    const int s0  = sg * 4;
    const int w0  = wh * 64;
    const int t   = threadIdx.x;
    __shared__ __align__(16) float zl[4*1280];   // [sp][c][b]
    __shared__ __align__(16) float fl[4*20*64];  // [sp][c][w64]
    #pragma unroll
    for (int sp = 0; sp < 4; sp++) {
        const int srow = (s0 + sp) * 1280;
        for (int r = t; r < 1280; r += 256) {
            const float a0 = zg[srow + r];
            const float a1 = zg[512*1280 + srow + r];
            zl[sp*1280 + r] = silu_f((a0 + a1) * (1.f / (float)N_PTS));
        }
        for (int u = t; u < 1280; u += 256) {
            const int c = u >> 6, ww = u & 63;
            fl[sp*1280 + u] = f2g[(s0 + sp)*2560 + c*128 + w0 + ww];
        }
    }
    __syncthreads();
    const int ww = t & 63, bh = t >> 6;
    float4 acc[4];
    #pragma unroll
    for (int qq = 0; qq < 4; qq++) acc[qq] = make_float4(0.f, 0.f, 0.f, 0.f);
    #pragma unroll 4
    for (int sc = 0; sc < 80; sc++) {
        const float f = fl[sc * 64 + ww];
        const float4* zz = (const float4*)&zl[sc * 64 + bh * 16];
        #pragma unroll
        for (int qq = 0; qq < 4; qq++) fma4(acc[qq], f, zz[qq]);
    }
    const float* af = (const float*)acc;
    #pragma unroll
    for (int idx = 0; idx < 16; idx++) {
        const int b = bh * 16 + idx;
        atomicAdd(&out2g[b * 128 + w0 + ww], af[idx]);
    }
}

// ---------------------------------------------------------------------------
// K3: FC tail only (out2 already reduced by k2 atomics).
// ---------------------------------------------------------------------------
__global__ __launch_bounds__(128) void k3_tail(
    const float* __restrict__ out2g,
    const float* __restrict__ fc1w, const float* __restrict__ fc1b,
    const float* __restrict__ fc2w, const float* __restrict__ fc2b,
    const float* __restrict__ pw,   const float* __restrict__ pb,
    float* __restrict__ out)
{
    const int b = blockIdx.x, t = threadIdx.x;
    __shared__ float zb[128], r1[128], r2[128];
    zb[t] = out2g[b * 128 + t] * (1.f / (float)SNUM);
    __syncthreads();
    float a = fc1b[t];
    #pragma unroll 8
    for (int i = 0; i < 128; i++) a += zb[i] * fc1w[i * 128 + t];
    r1[t] = silu_f(a) + zb[t];
    __syncthreads();
    a = fc2b[t];
    #pragma unroll 8
    for (int i = 0; i < 128; i++) a += r1[i] * fc2w[i * 128 + t];
    r2[t] = silu_f(a) + r1[t];
    __syncthreads();
    if (t < 10) {
        float o = pb[t];
        #pragma unroll 8
        for (int i = 0; i < 128; i++) o += r2[i] * pw[i * 10 + t];
        out[b * 10 + t] = o;
    }
}

extern "C" void kernel_launch(void* const* d_in, const int* in_sizes, int n_in,
                              void* d_out, int out_size, void* d_ws, size_t ws_size,
                              hipStream_t stream) {
    const float* data   = (const float*)d_in[0];
    const float* v0     = (const float*)d_in[1];
    const float* v_last = (const float*)d_in[2];
    const float* fl_w1  = (const float*)d_in[3];
    const float* fl_b1  = (const float*)d_in[4];
    const float* fl_w2  = (const float*)d_in[5];
    const float* fl_b2  = (const float*)d_in[6];
    const float* fl_w3  = (const float*)d_in[7];
    const float* fl_b3  = (const float*)d_in[8];
    const float* s_w1   = (const float*)d_in[9];
    const float* s_b1   = (const float*)d_in[10];
    const float* s_w2   = (const float*)d_in[11];
    const float* s_b2   = (const float*)d_in[12];
    const float* fc1_w  = (const float*)d_in[13];
    const float* fc1_b  = (const float*)d_in[14];
    const float* fc2_w  = (const float*)d_in[15];
    const float* fc2_b  = (const float*)d_in[16];
    const float* pool_w = (const float*)d_in[17];
    const float* pool_b = (const float*)d_in[18];
    float* out = (float*)d_out;

    float* ws        = (float*)d_ws;
    _Float16* dataA  = (_Float16*)ws;        // 102400 halves = 51200 float slots
    float* zpart  = ws    + 51200;           // 2*655360 [half][s][c][b] raw
    float* f2g    = zpart + 1310720;         // 1310720  [s][c*128+w]
    float* out2g  = f2g   + 1310720;         // 8192 [b][w] atomic accumulator
    _Float16* wPackA = (_Float16*)(out2g + 8192);    // 3072 halves
    float* bPackA = out2g + 8192 + 1536;     // 96 floats
    // total ~10.9 MB

    ka_prep    <<<371, 256, 0, stream>>>(data, v0, s_w1, s_b1, s_w2, s_b2,
                                         fl_w1, fl_b1, fl_w2, fl_b2, fl_w3, fl_b3,
                                         dataA, f2g, wPackA, bPackA, out2g);
    k1_filt_z  <<<1024, 256, 0, stream>>>(dataA, v_last, wPackA, bPackA, zpart);
    k2_contract<<<256, 256, 0, stream>>>(zpart, f2g, out2g);
    k3_tail    <<<64, 128, 0, stream>>>(out2g, fc1_w, fc1_b, fc2_w, fc2_b,
                                        pool_w, pool_b, out);
}